// Round 3
// baseline (32648.645 us; speedup 1.0000x reference)
//
#include <hip/hip_runtime.h>
#include <stdint.h>
#include <stddef.h>

#define B_ 128
#define T_ 256
#define I_ 256
#define H_ 1024
#define O_ 128

typedef __attribute__((ext_vector_type(8))) __bf16 bf16x8;
typedef __attribute__((ext_vector_type(4))) float f32x4;

// ---------------------------------------------------------------- utilities

__global__ void split_kernel(const float* __restrict__ src, __bf16* __restrict__ hi,
                             __bf16* __restrict__ lo, int n) {
    int i = blockIdx.x * blockDim.x + threadIdx.x;
    int stride = gridDim.x * blockDim.x;
    for (; i < n; i += stride) {
        float v = src[i];
        __bf16 h = (__bf16)v;               // RNE
        hi[i] = h;
        lo[i] = (__bf16)(v - (float)h);
    }
}

__global__ void bias_sum_kernel(const float* __restrict__ a, const float* __restrict__ b,
                                float* __restrict__ o, int n) {
    int i = blockIdx.x * blockDim.x + threadIdx.x;
    if (i < n) o[i] = a[i] + b[i];
}

__global__ void transpose_fc(const float* __restrict__ w, float* __restrict__ wt) {
    int i = blockIdx.x * blockDim.x + threadIdx.x;
    if (i < O_ * H_) {
        int o = i / H_, k = i - o * H_;
        wt[k * O_ + o] = w[i];
    }
}

__device__ __forceinline__ void mfma3(f32x4* acc, bf16x8 ah, bf16x8 al,
                                      bf16x8 bh, bf16x8 bl) {
    acc[0] = __builtin_amdgcn_mfma_f32_16x16x32_bf16(ah, bh, acc[0], 0, 0, 0);
    acc[1] = __builtin_amdgcn_mfma_f32_16x16x32_bf16(al, bh, acc[1], 0, 0, 0);
    acc[2] = __builtin_amdgcn_mfma_f32_16x16x32_bf16(ah, bl, acc[2], 0, 0, 0);
}

// ---------------------------------------------------------------- tile step
// 16x32 C-tile, 4-wave K-split, 3-term hi/lo MFMA, LDS reduce, tanh epilogue.
__device__ __forceinline__ void step_tile(
    const __bf16* __restrict__ Ah, const __bf16* __restrict__ Al, long lda, int K0,
    const __bf16* __restrict__ Wih, const __bf16* __restrict__ Wil,
    const __bf16* __restrict__ Wrh, const __bf16* __restrict__ Wrl,
    const __bf16* __restrict__ Sh,  const __bf16* __restrict__ Sl,
    const float* __restrict__ bs,
    __bf16* __restrict__ Oh, __bf16* __restrict__ Ol,
    __bf16* __restrict__ Qh, __bf16* __restrict__ Ql, long ldq,
    int bt, int jt, float* red)
{
    const int wave = threadIdx.x >> 6;
    const int lane = threadIdx.x & 63;
    const int ln = lane & 15;
    const int q  = lane >> 4;

    const int Ktot = K0 + H_;
    const int Kq = Ktot >> 2;
    const int kbeg = wave * Kq;
    const int kend = kbeg + Kq;

    const int arow = bt * 16 + ln;
    const int br0 = jt * 32 + ln;
    const int br1 = br0 + 16;

    f32x4 acc0[3] = {{0,0,0,0},{0,0,0,0},{0,0,0,0}};
    f32x4 acc1[3] = {{0,0,0,0},{0,0,0,0},{0,0,0,0}};

    // segment 0: input contribution (Wih rows, stride K0)
    {
        int sb = kbeg, se = kend < K0 ? kend : K0;
        if (se > sb) {
            const __bf16* ap_h = Ah + (long)arow * lda + sb + q * 8;
            const __bf16* ap_l = Al + (long)arow * lda + sb + q * 8;
            const __bf16* b0h = Wih + (long)br0 * K0 + sb + q * 8;
            const __bf16* b0l = Wil + (long)br0 * K0 + sb + q * 8;
            const __bf16* b1h = Wih + (long)br1 * K0 + sb + q * 8;
            const __bf16* b1l = Wil + (long)br1 * K0 + sb + q * 8;
            int n = (se - sb) >> 5;
            #pragma unroll 2
            for (int c = 0; c < n; ++c) {
                bf16x8 a_h = *(const bf16x8*)(ap_h + c * 32);
                bf16x8 a_l = *(const bf16x8*)(ap_l + c * 32);
                bf16x8 w0h = *(const bf16x8*)(b0h + c * 32);
                bf16x8 w0l = *(const bf16x8*)(b0l + c * 32);
                bf16x8 w1h = *(const bf16x8*)(b1h + c * 32);
                bf16x8 w1l = *(const bf16x8*)(b1l + c * 32);
                mfma3(acc0, a_h, a_l, w0h, w0l);
                mfma3(acc1, a_h, a_l, w1h, w1l);
            }
        }
    }
    // segment 1: recurrent contribution (state + Wr, stride H_)
    {
        int sb = kbeg > K0 ? kbeg - K0 : 0;
        int se = kend - K0;
        if (se > sb) {
            const __bf16* ap_h = Sh + (long)arow * H_ + sb + q * 8;
            const __bf16* ap_l = Sl + (long)arow * H_ + sb + q * 8;
            const __bf16* b0h = Wrh + (long)br0 * H_ + sb + q * 8;
            const __bf16* b0l = Wrl + (long)br0 * H_ + sb + q * 8;
            const __bf16* b1h = Wrh + (long)br1 * H_ + sb + q * 8;
            const __bf16* b1l = Wrl + (long)br1 * H_ + sb + q * 8;
            int n = (se - sb) >> 5;
            #pragma unroll 2
            for (int c = 0; c < n; ++c) {
                bf16x8 a_h = *(const bf16x8*)(ap_h + c * 32);
                bf16x8 a_l = *(const bf16x8*)(ap_l + c * 32);
                bf16x8 w0h = *(const bf16x8*)(b0h + c * 32);
                bf16x8 w0l = *(const bf16x8*)(b0l + c * 32);
                bf16x8 w1h = *(const bf16x8*)(b1h + c * 32);
                bf16x8 w1l = *(const bf16x8*)(b1l + c * 32);
                mfma3(acc0, a_h, a_l, w0h, w0l);
                mfma3(acc1, a_h, a_l, w1h, w1l);
            }
        }
    }

    // LDS reduction across 4 K-split waves (pad 33 to kill bank conflicts)
    {
        float* my = red + wave * 528;
        f32x4 s0 = acc0[0] + acc0[1] + acc0[2];
        f32x4 s1 = acc1[0] + acc1[1] + acc1[2];
        // C/D layout: col=lane&15, row=(lane>>4)*4+r  [m89/m91]
        #pragma unroll
        for (int r = 0; r < 4; ++r) {
            my[(q * 4 + r) * 33 + ln] = s0[r];
            my[(q * 4 + r) * 33 + 16 + ln] = s1[r];
        }
    }
    __syncthreads();

    #pragma unroll
    for (int e = 0; e < 2; ++e) {
        int idx = threadIdx.x + e * 256;
        int row = idx >> 5;
        int col = idx & 31;
        int off = row * 33 + col;
        float v = red[off] + red[528 + off] + red[1056 + off] + red[1584 + off];
        int b = bt * 16 + row;
        int j = jt * 32 + col;
        float h = tanhf(v + bs[j]);
        __bf16 hh = (__bf16)h;
        __bf16 hl = (__bf16)(h - (float)hh);
        Oh[(long)b * H_ + j] = hh;
        Ol[(long)b * H_ + j] = hl;
        if (Qh) { Qh[(long)b * ldq + j] = hh; Ql[(long)b * ldq + j] = hl; }
    }
}

// ---------------------------------------------------------------- barrier
// Two-level device barrier: 8 arrive counters (by blockIdx&7, 128B apart),
// master (block 0) aggregates and publishes replicated epoch flags.
__device__ __forceinline__ void grid_barrier(unsigned* bar, int grp, unsigned step) {
    __syncthreads();   // drains vmcnt(0): all block stores are in L2 before release
    if (threadIdx.x == 0) {
        unsigned tgt = step + 1u;
        __hip_atomic_fetch_add(&bar[grp * 32], 1u, __ATOMIC_RELEASE,
                               __HIP_MEMORY_SCOPE_AGENT);
        if (blockIdx.x == 0) {
            for (int i = 0; i < 8; ++i) {
                while (__hip_atomic_load(&bar[i * 32], __ATOMIC_ACQUIRE,
                                         __HIP_MEMORY_SCOPE_AGENT) < tgt * 64u)
                    __builtin_amdgcn_s_sleep(1);
            }
            for (int i = 0; i < 8; ++i)
                __hip_atomic_store(&bar[512 + i * 32], tgt, __ATOMIC_RELEASE,
                                   __HIP_MEMORY_SCOPE_AGENT);
        } else {
            while (__hip_atomic_load(&bar[512 + grp * 32], __ATOMIC_ACQUIRE,
                                     __HIP_MEMORY_SCOPE_AGENT) < tgt)
                __builtin_amdgcn_s_sleep(1);
        }
    }
    __syncthreads();
}

// ---------------------------------------------------------------- persistent
struct PArgs {
    const __bf16 *Xh, *Xl;
    const __bf16 *Wi0h, *Wi0l, *Wr0h, *Wr0l;
    const __bf16 *Wi1h, *Wi1l, *Wr1h, *Wr1l;
    const float *bs0, *bs1;
    __bf16 *h1h, *h1l;
    __bf16 *s0ah, *s0al, *s0bh, *s0bl;
    __bf16 *s1ah, *s1al, *s1bh, *s1bl;
    unsigned* bar;
};

// 512 blocks x 256 threads, 2 blocks/CU. Block role fixed for the whole run:
// grp = blockIdx&7 (intended XCD); within grp: 32 layer0 + 32 layer1 blocks
// covering a contiguous 4-jt (128-col) strip -> per-XCD L2 working set ~3.3MB.
__global__ __launch_bounds__(256, 2) void persistent_rnn(PArgs a) {
    __shared__ float red[4 * 16 * 33];
    const int grp = blockIdx.x & 7;
    const int local = blockIdx.x >> 3;     // 0..63
    const int layer = local >> 5;          // 0..1
    const int l5 = local & 31;
    const int jt = grp * 4 + (l5 & 3);     // 0..31
    const int bt = l5 >> 2;                // 0..7

    for (int t = 0; t <= T_; ++t) {
        if (layer == 0) {
            if (t < T_) {
                const __bf16 *sih, *sil; __bf16 *soh, *sol;
                if ((t & 1) == 0) { sih = a.s0ah; sil = a.s0al; soh = a.s0bh; sol = a.s0bl; }
                else              { sih = a.s0bh; sil = a.s0bl; soh = a.s0ah; sol = a.s0al; }
                step_tile(a.Xh + (long)t * I_, a.Xl + (long)t * I_, (long)T_ * I_, I_,
                          a.Wi0h, a.Wi0l, a.Wr0h, a.Wr0l, sih, sil, a.bs0,
                          soh, sol, a.h1h + (long)t * H_, a.h1l + (long)t * H_,
                          (long)T_ * H_, bt, jt, red);
            }
        } else {
            if (t >= 1) {
                int t1 = t - 1;
                const __bf16 *sih, *sil; __bf16 *soh, *sol;
                if ((t1 & 1) == 0) { sih = a.s1ah; sil = a.s1al; soh = a.s1bh; sol = a.s1bl; }
                else               { sih = a.s1bh; sil = a.s1bl; soh = a.s1ah; sol = a.s1al; }
                step_tile(a.h1h + (long)t1 * H_, a.h1l + (long)t1 * H_, (long)T_ * H_, H_,
                          a.Wi1h, a.Wi1l, a.Wr1h, a.Wr1l, sih, sil, a.bs1,
                          soh, sol, (__bf16*)nullptr, (__bf16*)nullptr, 0,
                          bt, jt, red);
            }
        }
        grid_barrier(a.bar, grp, (unsigned)t);
    }
}

// ---------------------------------------------------------------- final FC
__global__ __launch_bounds__(128) void fc_kernel(const __bf16* __restrict__ sh,
                                                 const __bf16* __restrict__ sl,
                                                 const float* __restrict__ wt,
                                                 const float* __restrict__ bfc,
                                                 float* __restrict__ out) {
    int b = blockIdx.x;
    int o = threadIdx.x;
    const __bf16* hh = sh + (long)b * H_;
    const __bf16* hl = sl + (long)b * H_;
    float acc = 0.f;
    #pragma unroll 4
    for (int k = 0; k < H_; ++k)
        acc += ((float)hh[k] + (float)hl[k]) * wt[k * O_ + o];
    out[b * O_ + o] = acc + bfc[o];
}

// ---------------------------------------------------------------- launch

extern "C" void kernel_launch(void* const* d_in, const int* in_sizes, int n_in,
                              void* d_out, int out_size, void* d_ws, size_t ws_size,
                              hipStream_t stream) {
    const float* X     = (const float*)d_in[0];
    const float* Wih0  = (const float*)d_in[1];
    const float* Whh0  = (const float*)d_in[2];
    const float* bih0  = (const float*)d_in[3];
    const float* bhh0  = (const float*)d_in[4];
    const float* Wih1  = (const float*)d_in[5];
    const float* Whh1  = (const float*)d_in[6];
    const float* bih1  = (const float*)d_in[7];
    const float* bhh1  = (const float*)d_in[8];
    const float* Wfc   = (const float*)d_in[9];
    const float* bfc   = (const float*)d_in[10];
    float* out = (float*)d_out;

    char* p = (char*)d_ws;
    auto alloc = [&](size_t bytes) -> void* {
        void* r = (void*)p;
        p += (bytes + 255) & ~(size_t)255;
        return r;
    };
    const size_t nX  = (size_t)B_ * T_ * I_;
    const size_t nW0 = (size_t)H_ * I_;
    const size_t nW  = (size_t)H_ * H_;
    const size_t nH1 = (size_t)B_ * T_ * H_;
    const size_t nS  = (size_t)B_ * H_;
    __bf16* Xh   = (__bf16*)alloc(nX * 2);
    __bf16* Xl   = (__bf16*)alloc(nX * 2);
    __bf16* W0h  = (__bf16*)alloc(nW0 * 2);
    __bf16* W0l  = (__bf16*)alloc(nW0 * 2);
    __bf16* Wh0h = (__bf16*)alloc(nW * 2);
    __bf16* Wh0l = (__bf16*)alloc(nW * 2);
    __bf16* Wi1h = (__bf16*)alloc(nW * 2);
    __bf16* Wi1l = (__bf16*)alloc(nW * 2);
    __bf16* Wh1h = (__bf16*)alloc(nW * 2);
    __bf16* Wh1l = (__bf16*)alloc(nW * 2);
    __bf16* h1h  = (__bf16*)alloc(nH1 * 2);
    __bf16* h1l  = (__bf16*)alloc(nH1 * 2);
    __bf16* s0ah = (__bf16*)alloc(nS * 2);
    __bf16* s0al = (__bf16*)alloc(nS * 2);
    __bf16* s0bh = (__bf16*)alloc(nS * 2);
    __bf16* s0bl = (__bf16*)alloc(nS * 2);
    __bf16* s1ah = (__bf16*)alloc(nS * 2);
    __bf16* s1al = (__bf16*)alloc(nS * 2);
    __bf16* s1bh = (__bf16*)alloc(nS * 2);
    __bf16* s1bl = (__bf16*)alloc(nS * 2);
    float* wfct  = (float*)alloc((size_t)H_ * O_ * 4);
    float* bs0   = (float*)alloc((size_t)H_ * 4);
    float* bs1   = (float*)alloc((size_t)H_ * 4);
    unsigned* bar = (unsigned*)alloc(4096);
    (void)ws_size; (void)n_in; (void)in_sizes; (void)out_size;

    split_kernel<<<2048, 256, 0, stream>>>(X, Xh, Xl, (int)nX);
    split_kernel<<<512, 256, 0, stream>>>(Wih0, W0h, W0l, (int)nW0);
    split_kernel<<<1024, 256, 0, stream>>>(Whh0, Wh0h, Wh0l, (int)nW);
    split_kernel<<<1024, 256, 0, stream>>>(Wih1, Wi1h, Wi1l, (int)nW);
    split_kernel<<<1024, 256, 0, stream>>>(Whh1, Wh1h, Wh1l, (int)nW);
    bias_sum_kernel<<<4, 256, 0, stream>>>(bih0, bhh0, bs0, H_);
    bias_sum_kernel<<<4, 256, 0, stream>>>(bih1, bhh1, bs1, H_);
    transpose_fc<<<(O_ * H_ + 255) / 256, 256, 0, stream>>>(Wfc, wfct);

    hipMemsetAsync(s0ah, 0, nS * 2, stream);
    hipMemsetAsync(s0al, 0, nS * 2, stream);
    hipMemsetAsync(s1ah, 0, nS * 2, stream);
    hipMemsetAsync(s1al, 0, nS * 2, stream);
    hipMemsetAsync(bar, 0, 4096, stream);

    PArgs args;
    args.Xh = Xh; args.Xl = Xl;
    args.Wi0h = W0h; args.Wi0l = W0l; args.Wr0h = Wh0h; args.Wr0l = Wh0l;
    args.Wi1h = Wi1h; args.Wi1l = Wi1l; args.Wr1h = Wh1h; args.Wr1l = Wh1l;
    args.bs0 = bs0; args.bs1 = bs1;
    args.h1h = h1h; args.h1l = h1l;
    args.s0ah = s0ah; args.s0al = s0al; args.s0bh = s0bh; args.s0bl = s0bl;
    args.s1ah = s1ah; args.s1al = s1al; args.s1bh = s1bh; args.s1bl = s1bl;
    args.bar = bar;
    void* kp[] = { &args };
    hipLaunchCooperativeKernel((void*)persistent_rnn, dim3(512), dim3(256), kp, 0, stream);

    // final layer1 state: last t1=255 (odd) wrote the A buffers
    fc_kernel<<<B_, O_, 0, stream>>>(s1ah, s1al, wfct, bfc, out);
}

// Round 4
// 5154.101 us; speedup vs baseline: 6.3345x; 6.3345x over previous
//
#include <hip/hip_runtime.h>
#include <stdint.h>
#include <stddef.h>

#define B_ 128
#define T_ 256
#define I_ 256
#define H_ 1024
#define O_ 128

typedef __attribute__((ext_vector_type(8))) __bf16 bf16x8;
typedef __attribute__((ext_vector_type(4))) float f32x4;
typedef unsigned long long u64;

// Packed-swizzled state layout (per layer, K columns, 128 batch rows):
//   element (b, k):  bt = b>>4, ln = b&15
//   u64 index = bt*(K/2)*16 + (k/2)*16 + ln
//   u64 value = dword(k even) | dword(k odd)<<32, dword = hh_bits | hl_bits<<16
// This puts the wave's 64 lanes of each atomic load on contiguous addresses
// (8 lines / 512B instr) and matches the MFMA A-fragment order (k = q*8+j).

// ---------------------------------------------------------------- utilities

__global__ void split_kernel(const float* __restrict__ src, __bf16* __restrict__ hi,
                             __bf16* __restrict__ lo, int n) {
    int i = blockIdx.x * blockDim.x + threadIdx.x;
    int stride = gridDim.x * blockDim.x;
    for (; i < n; i += stride) {
        float v = src[i];
        __bf16 h = (__bf16)v;               // RNE
        hi[i] = h;
        lo[i] = (__bf16)(v - (float)h);
    }
}

__global__ void bias_sum_kernel(const float* __restrict__ a, const float* __restrict__ b,
                                float* __restrict__ o, int n) {
    int i = blockIdx.x * blockDim.x + threadIdx.x;
    if (i < n) o[i] = a[i] + b[i];
}

__global__ void transpose_fc(const float* __restrict__ w, float* __restrict__ wt) {
    int i = blockIdx.x * blockDim.x + threadIdx.x;
    if (i < O_ * H_) {
        int o = i / H_, k = i - o * H_;
        wt[k * O_ + o] = w[i];
    }
}

__device__ __forceinline__ void mfma3(f32x4* acc, bf16x8 ah, bf16x8 al,
                                      bf16x8 bh, bf16x8 bl) {
    acc[0] = __builtin_amdgcn_mfma_f32_16x16x32_bf16(ah, bh, acc[0], 0, 0, 0);
    acc[1] = __builtin_amdgcn_mfma_f32_16x16x32_bf16(al, bh, acc[1], 0, 0, 0);
    acc[2] = __builtin_amdgcn_mfma_f32_16x16x32_bf16(ah, bl, acc[2], 0, 0, 0);
}

// Load one A-fragment chunk (8 k's for this lane) from packed-swizzled buffer
// via 4 relaxed agent-scope (sc1, LLC-coherent, no fence) 64-bit atomic loads.
__device__ __forceinline__ void load_swz(const u64* p, bf16x8* hi, bf16x8* lo) {
    u64 d[4];
    #pragma unroll
    for (int i = 0; i < 4; ++i)
        d[i] = __hip_atomic_load((u64*)p + i * 16, __ATOMIC_RELAXED,
                                 __HIP_MEMORY_SCOPE_AGENT);
    union { unsigned u[4]; bf16x8 v; } H, L;
    #pragma unroll
    for (int i = 0; i < 4; ++i) {
        unsigned lo32 = (unsigned)d[i], hi32 = (unsigned)(d[i] >> 32);
        H.u[i] = (lo32 & 0xFFFFu) | (hi32 << 16);
        L.u[i] = (lo32 >> 16) | (hi32 & 0xFFFF0000u);
    }
    *hi = H.v; *lo = L.v;
}

// ---------------------------------------------------------------- tile step
// 16x32 C-tile, 4-wave K-split, 3-term hi/lo MFMA, LDS reduce, tanh epilogue.
__device__ __forceinline__ void step_tile(
    const __bf16* __restrict__ Axh, const __bf16* __restrict__ Axl, long ldax, // seg0 planes (x) or null
    const u64* Ap0,                                                            // seg0 packed (h1) if Axh==null
    int K0,
    const __bf16* __restrict__ Wih, const __bf16* __restrict__ Wil,            // stride K0
    const u64* Sp,                                                             // packed state (K=H_)
    const __bf16* __restrict__ Wrh, const __bf16* __restrict__ Wrl,            // stride H_
    const float* __restrict__ bs,
    u64* So,                                                                   // packed state out
    u64* Qo,                                                                   // packed h1 out (or null)
    int bt, int jt, float* red)
{
    const int wave = threadIdx.x >> 6;
    const int lane = threadIdx.x & 63;
    const int ln = lane & 15;
    const int q  = lane >> 4;

    const int Ktot = K0 + H_;
    const int Kq = Ktot >> 2;
    const int kbeg = wave * Kq;
    const int kend = kbeg + Kq;

    const int arow = bt * 16 + ln;
    const int br0 = jt * 32 + ln;
    const int br1 = br0 + 16;

    f32x4 acc0[3] = {{0,0,0,0},{0,0,0,0},{0,0,0,0}};
    f32x4 acc1[3] = {{0,0,0,0},{0,0,0,0},{0,0,0,0}};

    // ---- segment 0: input contribution (x planes, or packed h1)
    {
        int sb = kbeg, se = kend < K0 ? kend : K0;
        if (se > sb) {
            const __bf16* b0h = Wih + (long)br0 * K0 + sb + q * 8;
            const __bf16* b0l = Wil + (long)br0 * K0 + sb + q * 8;
            const __bf16* b1h = Wih + (long)br1 * K0 + sb + q * 8;
            const __bf16* b1l = Wil + (long)br1 * K0 + sb + q * 8;
            int n = (se - sb) >> 5;
            if (Axh) {  // x: normal cached plane loads
                const __bf16* ap_h = Axh + (long)arow * ldax + sb + q * 8;
                const __bf16* ap_l = Axl + (long)arow * ldax + sb + q * 8;
                #pragma unroll 2
                for (int c = 0; c < n; ++c) {
                    bf16x8 a_h = *(const bf16x8*)(ap_h + c * 32);
                    bf16x8 a_l = *(const bf16x8*)(ap_l + c * 32);
                    bf16x8 w0h = *(const bf16x8*)(b0h + c * 32);
                    bf16x8 w0l = *(const bf16x8*)(b0l + c * 32);
                    bf16x8 w1h = *(const bf16x8*)(b1h + c * 32);
                    bf16x8 w1l = *(const bf16x8*)(b1l + c * 32);
                    mfma3(acc0, a_h, a_l, w0h, w0l);
                    mfma3(acc1, a_h, a_l, w1h, w1l);
                }
            } else {    // h1: packed-swizzled sc1 loads
                const u64* ap = Ap0 + (long)bt * ((K0 >> 1) * 16)
                              + ((sb >> 1) + q * 4) * 16 + ln;
                #pragma unroll 2
                for (int c = 0; c < n; ++c) {
                    bf16x8 a_h, a_l;
                    load_swz(ap + c * 256, &a_h, &a_l);
                    bf16x8 w0h = *(const bf16x8*)(b0h + c * 32);
                    bf16x8 w0l = *(const bf16x8*)(b0l + c * 32);
                    bf16x8 w1h = *(const bf16x8*)(b1h + c * 32);
                    bf16x8 w1l = *(const bf16x8*)(b1l + c * 32);
                    mfma3(acc0, a_h, a_l, w0h, w0l);
                    mfma3(acc1, a_h, a_l, w1h, w1l);
                }
            }
        }
    }
    // ---- segment 1: recurrent contribution (packed state + Wr planes)
    {
        int sb = kbeg > K0 ? kbeg - K0 : 0;
        int se = kend - K0;
        if (se > sb) {
            const u64* ap = Sp + (long)bt * ((H_ >> 1) * 16)
                          + ((sb >> 1) + q * 4) * 16 + ln;
            const __bf16* b0h = Wrh + (long)br0 * H_ + sb + q * 8;
            const __bf16* b0l = Wrl + (long)br0 * H_ + sb + q * 8;
            const __bf16* b1h = Wrh + (long)br1 * H_ + sb + q * 8;
            const __bf16* b1l = Wrl + (long)br1 * H_ + sb + q * 8;
            int n = (se - sb) >> 5;
            #pragma unroll 2
            for (int c = 0; c < n; ++c) {
                bf16x8 a_h, a_l;
                load_swz(ap + c * 256, &a_h, &a_l);
                bf16x8 w0h = *(const bf16x8*)(b0h + c * 32);
                bf16x8 w0l = *(const bf16x8*)(b0l + c * 32);
                bf16x8 w1h = *(const bf16x8*)(b1h + c * 32);
                bf16x8 w1l = *(const bf16x8*)(b1l + c * 32);
                mfma3(acc0, a_h, a_l, w0h, w0l);
                mfma3(acc1, a_h, a_l, w1h, w1l);
            }
        }
    }

    // ---- LDS reduction across 4 K-split waves (pad 33)
    {
        float* my = red + wave * 528;
        f32x4 s0 = acc0[0] + acc0[1] + acc0[2];
        f32x4 s1 = acc1[0] + acc1[1] + acc1[2];
        // C/D layout: col=lane&15, row=(lane>>4)*4+r  [m89/m91]
        #pragma unroll
        for (int r = 0; r < 4; ++r) {
            my[(q * 4 + r) * 33 + ln] = s0[r];
            my[(q * 4 + r) * 33 + 16 + ln] = s1[r];
        }
    }
    __syncthreads();

    // ---- epilogue: 256 u64 outputs (one per thread), packed-swizzled sc1 store
    {
        int row = threadIdx.x & 15;      // = ln of consumer
        int jp  = threadIdx.x >> 4;      // j-pair 0..15
        int c0 = jp * 2;
        float v0 = red[row * 33 + c0]       + red[528 + row * 33 + c0]
                 + red[1056 + row * 33 + c0] + red[1584 + row * 33 + c0];
        float v1 = red[row * 33 + c0 + 1]       + red[528 + row * 33 + c0 + 1]
                 + red[1056 + row * 33 + c0 + 1] + red[1584 + row * 33 + c0 + 1];
        int j0 = jt * 32 + c0;
        float h0 = tanhf(v0 + bs[j0]);
        float h1v = tanhf(v1 + bs[j0 + 1]);
        union { __bf16 b; unsigned short u; } x0h, x0l, x1h, x1l;
        x0h.b = (__bf16)h0;  x0l.b = (__bf16)(h0 - (float)x0h.b);
        x1h.b = (__bf16)h1v; x1l.b = (__bf16)(h1v - (float)x1h.b);
        u64 pk = (u64)((unsigned)x0h.u | ((unsigned)x0l.u << 16))
               | ((u64)((unsigned)x1h.u | ((unsigned)x1l.u << 16)) << 32);
        long idx = (long)bt * 8192 + (long)(jt * 16 + jp) * 16 + row;
        __hip_atomic_store(&So[idx], pk, __ATOMIC_RELAXED, __HIP_MEMORY_SCOPE_AGENT);
        if (Qo)
            __hip_atomic_store(&Qo[idx], pk, __ATOMIC_RELAXED, __HIP_MEMORY_SCOPE_AGENT);
    }
}

// ---------------------------------------------------------------- barrier
// Fence-free global barrier: relaxed agent-scope atomics only (sc1 ops meet at
// the coherent LLC). NO acquire/release -> NO buffer_inv/buffer_wbl2 -> XCD L2
// weight residency survives across steps (the r3 killer). Ordering: each wave
// drains its sc1 stores (vmcnt ack = reached LLC) before thread 0 arrives.
__device__ __forceinline__ void grid_barrier(unsigned* bar, int grp, unsigned step) {
    asm volatile("s_waitcnt vmcnt(0)" ::: "memory");
    __syncthreads();
    if (threadIdx.x == 0) {
        unsigned tgt = step + 1u;
        unsigned old = __hip_atomic_fetch_add(&bar[grp * 32], 1u, __ATOMIC_RELAXED,
                                              __HIP_MEMORY_SCOPE_AGENT);
        if ((old & 63u) == 63u) {          // last block of this 64-block group
            unsigned so = __hip_atomic_fetch_add(&bar[256], 1u, __ATOMIC_RELAXED,
                                                 __HIP_MEMORY_SCOPE_AGENT);
            if ((so & 7u) == 7u) {         // last group: release everyone
                #pragma unroll
                for (int i = 0; i < 8; ++i)
                    __hip_atomic_store(&bar[512 + i * 32], tgt, __ATOMIC_RELAXED,
                                       __HIP_MEMORY_SCOPE_AGENT);
            }
        }
        while (__hip_atomic_load(&bar[512 + grp * 32], __ATOMIC_RELAXED,
                                 __HIP_MEMORY_SCOPE_AGENT) < tgt)
            __builtin_amdgcn_s_sleep(2);
    }
    __syncthreads();
    asm volatile("" ::: "memory");
}

// ---------------------------------------------------------------- persistent
struct PArgs {
    const __bf16 *Xh, *Xl;
    const __bf16 *Wi0h, *Wi0l, *Wr0h, *Wr0l;
    const __bf16 *Wi1h, *Wi1l, *Wr1h, *Wr1l;
    const float *bs0, *bs1;
    u64 *h1;                       // [T][bt][k/2][ln] packed-swizzled
    u64 *s0a, *s0b, *s1a, *s1b;    // [bt][k/2][ln] packed-swizzled
    unsigned* bar;
};

__global__ __launch_bounds__(256, 2) void persistent_rnn(PArgs a) {
    __shared__ float red[4 * 16 * 33];
    const int grp = blockIdx.x & 7;
    const int local = blockIdx.x >> 3;     // 0..63
    const int layer = local >> 5;          // 0..1
    const int l5 = local & 31;
    const int jt = grp * 4 + (l5 & 3);     // 0..31
    const int bt = l5 >> 2;                // 0..7

    for (int t = 0; t <= T_; ++t) {
        if (layer == 0) {
            if (t < T_) {
                const u64* sin = (t & 1) ? a.s0b : a.s0a;
                u64* sout      = (t & 1) ? a.s0a : a.s0b;
                step_tile(a.Xh + (long)t * I_, a.Xl + (long)t * I_, (long)T_ * I_,
                          (const u64*)nullptr, I_,
                          a.Wi0h, a.Wi0l, sin, a.Wr0h, a.Wr0l, a.bs0,
                          sout, a.h1 + (long)t * 65536, bt, jt, red);
            }
        } else {
            if (t >= 1) {
                int t1 = t - 1;
                const u64* sin = (t1 & 1) ? a.s1b : a.s1a;
                u64* sout      = (t1 & 1) ? a.s1a : a.s1b;
                step_tile((const __bf16*)nullptr, (const __bf16*)nullptr, 0,
                          a.h1 + (long)t1 * 65536, H_,
                          a.Wi1h, a.Wi1l, sin, a.Wr1h, a.Wr1l, a.bs1,
                          sout, (u64*)nullptr, bt, jt, red);
            }
        }
        grid_barrier(a.bar, grp, (unsigned)t);
    }
}

// ---------------------------------------------------------------- final FC
// Reads the packed-swizzled final state via sc1 loads (bypass possibly-stale L2).
__global__ __launch_bounds__(128) void fc_kernel(const u64* __restrict__ sp,
                                                 const float* __restrict__ wt,
                                                 const float* __restrict__ bfc,
                                                 float* __restrict__ out) {
    int b = blockIdx.x;
    int o = threadIdx.x;
    int bt = b >> 4, r = b & 15;
    float acc = 0.f;
    #pragma unroll 4
    for (int k2 = 0; k2 < H_ / 2; ++k2) {
        u64 pk = __hip_atomic_load((u64*)sp + (long)bt * 8192 + (long)k2 * 16 + r,
                                   __ATOMIC_RELAXED, __HIP_MEMORY_SCOPE_AGENT);
        union { unsigned short u; __bf16 bf; } hh, hl;
        unsigned lo32 = (unsigned)pk, hi32 = (unsigned)(pk >> 32);
        hh.u = (unsigned short)(lo32 & 0xFFFF); hl.u = (unsigned short)(lo32 >> 16);
        float x0 = (float)hh.bf + (float)hl.bf;
        hh.u = (unsigned short)(hi32 & 0xFFFF); hl.u = (unsigned short)(hi32 >> 16);
        float x1 = (float)hh.bf + (float)hl.bf;
        acc += x0 * wt[(2 * k2) * O_ + o] + x1 * wt[(2 * k2 + 1) * O_ + o];
    }
    out[b * O_ + o] = acc + bfc[o];
}

// ---------------------------------------------------------------- launch

extern "C" void kernel_launch(void* const* d_in, const int* in_sizes, int n_in,
                              void* d_out, int out_size, void* d_ws, size_t ws_size,
                              hipStream_t stream) {
    const float* X     = (const float*)d_in[0];
    const float* Wih0  = (const float*)d_in[1];
    const float* Whh0  = (const float*)d_in[2];
    const float* bih0  = (const float*)d_in[3];
    const float* bhh0  = (const float*)d_in[4];
    const float* Wih1  = (const float*)d_in[5];
    const float* Whh1  = (const float*)d_in[6];
    const float* bih1  = (const float*)d_in[7];
    const float* bhh1  = (const float*)d_in[8];
    const float* Wfc   = (const float*)d_in[9];
    const float* bfc   = (const float*)d_in[10];
    float* out = (float*)d_out;

    char* p = (char*)d_ws;
    auto alloc = [&](size_t bytes) -> void* {
        void* r = (void*)p;
        p += (bytes + 255) & ~(size_t)255;
        return r;
    };
    const size_t nX  = (size_t)B_ * T_ * I_;
    const size_t nW0 = (size_t)H_ * I_;
    const size_t nW  = (size_t)H_ * H_;
    __bf16* Xh   = (__bf16*)alloc(nX * 2);
    __bf16* Xl   = (__bf16*)alloc(nX * 2);
    __bf16* W0h  = (__bf16*)alloc(nW0 * 2);
    __bf16* W0l  = (__bf16*)alloc(nW0 * 2);
    __bf16* Wh0h = (__bf16*)alloc(nW * 2);
    __bf16* Wh0l = (__bf16*)alloc(nW * 2);
    __bf16* Wi1h = (__bf16*)alloc(nW * 2);
    __bf16* Wi1l = (__bf16*)alloc(nW * 2);
    __bf16* Wh1h = (__bf16*)alloc(nW * 2);
    __bf16* Wh1l = (__bf16*)alloc(nW * 2);
    u64* h1   = (u64*)alloc((size_t)T_ * 65536 * 8);   // 134 MB packed-swizzled
    u64* s0a  = (u64*)alloc(65536 * 8);
    u64* s0b  = (u64*)alloc(65536 * 8);
    u64* s1a  = (u64*)alloc(65536 * 8);
    u64* s1b  = (u64*)alloc(65536 * 8);
    float* wfct = (float*)alloc((size_t)H_ * O_ * 4);
    float* bs0  = (float*)alloc((size_t)H_ * 4);
    float* bs1  = (float*)alloc((size_t)H_ * 4);
    unsigned* bar = (unsigned*)alloc(4096);
    (void)ws_size; (void)n_in; (void)in_sizes; (void)out_size;

    split_kernel<<<2048, 256, 0, stream>>>(X, Xh, Xl, (int)nX);
    split_kernel<<<512, 256, 0, stream>>>(Wih0, W0h, W0l, (int)nW0);
    split_kernel<<<1024, 256, 0, stream>>>(Whh0, Wh0h, Wh0l, (int)nW);
    split_kernel<<<1024, 256, 0, stream>>>(Wih1, Wi1h, Wi1l, (int)nW);
    split_kernel<<<1024, 256, 0, stream>>>(Whh1, Wh1h, Wh1l, (int)nW);
    bias_sum_kernel<<<4, 256, 0, stream>>>(bih0, bhh0, bs0, H_);
    bias_sum_kernel<<<4, 256, 0, stream>>>(bih1, bhh1, bs1, H_);
    transpose_fc<<<(O_ * H_ + 255) / 256, 256, 0, stream>>>(Wfc, wfct);

    hipMemsetAsync(s0a, 0, 65536 * 8, stream);
    hipMemsetAsync(s1a, 0, 65536 * 8, stream);
    hipMemsetAsync(bar, 0, 4096, stream);

    PArgs args;
    args.Xh = Xh; args.Xl = Xl;
    args.Wi0h = W0h; args.Wi0l = W0l; args.Wr0h = Wh0h; args.Wr0l = Wh0l;
    args.Wi1h = Wi1h; args.Wi1l = Wi1l; args.Wr1h = Wh1h; args.Wr1l = Wh1l;
    args.bs0 = bs0; args.bs1 = bs1;
    args.h1 = h1;
    args.s0a = s0a; args.s0b = s0b; args.s1a = s1a; args.s1b = s1b;
    args.bar = bar;
    void* kp[] = { &args };
    hipLaunchCooperativeKernel((void*)persistent_rnn, dim3(512), dim3(256), kp, 0, stream);

    // final layer1 state: last t1=255 (odd) wrote the A buffer
    fc_kernel<<<B_, O_, 0, stream>>>(s1a, wfct, bfc, out);
}

// Round 5
// 2187.211 us; speedup vs baseline: 14.9271x; 2.3565x over previous
//
#include <hip/hip_runtime.h>
#include <stdint.h>
#include <stddef.h>

#define B_ 128
#define T_ 256
#define I_ 256
#define H_ 1024
#define O_ 128

typedef __attribute__((ext_vector_type(8))) __bf16 bf16x8;
typedef __attribute__((ext_vector_type(4))) float f32x4;
typedef unsigned long long u64;

// Packed-swizzled layout for state/h1/x (per buffer of K columns, 128 rows):
//   element (b,k): u64 idx = (b>>4)*(K/2)*16 + (k>>1)*16 + (b&15)
//   u64 = dword(k even) | dword(k odd)<<32 ; dword = hi_bits | lo_bits<<16
// One wave instruction touches 4x128B contiguous segments; lands in MFMA
// A-fragment order (k = q*8+j).

// ---------------------------------------------------------------- setup

__global__ void split_kernel(const float* __restrict__ src, __bf16* __restrict__ hi,
                             __bf16* __restrict__ lo, int n) {
    int i = blockIdx.x * blockDim.x + threadIdx.x;
    int stride = gridDim.x * blockDim.x;
    for (; i < n; i += stride) {
        float v = src[i];
        __bf16 h = (__bf16)v;
        hi[i] = h;
        lo[i] = (__bf16)(v - (float)h);
    }
}

// X (B,T,I) fp32 -> packed-swizzled per t: xp[t][b>>4][k>>1][b&15]
__global__ void pack_x(const float* __restrict__ X, u64* __restrict__ xp) {
    int i = blockIdx.x * 256 + threadIdx.x;           // 0 .. 4194303
    int ln = i & 15;
    int k2 = (i >> 4) & 127;
    int bt16 = (i >> 11) & 7;
    int t = i >> 14;
    int b = bt16 * 16 + ln;
    long xo = (long)b * T_ * I_ + (long)t * I_ + k2 * 2;
    float v0 = X[xo], v1 = X[xo + 1];
    union { __bf16 b; unsigned short u; } h0, l0, h1, l1;
    h0.b = (__bf16)v0; l0.b = (__bf16)(v0 - (float)h0.b);
    h1.b = (__bf16)v1; l1.b = (__bf16)(v1 - (float)h1.b);
    u64 pk = (u64)((unsigned)h0.u | ((unsigned)l0.u << 16))
           | ((u64)((unsigned)h1.u | ((unsigned)l1.u << 16)) << 32);
    xp[(long)t * 16384 + bt16 * 2048 + k2 * 16 + ln] = pk;
}

__global__ void bias_sum_kernel(const float* __restrict__ a, const float* __restrict__ b,
                                float* __restrict__ o, int n) {
    int i = blockIdx.x * blockDim.x + threadIdx.x;
    if (i < n) o[i] = a[i] + b[i];
}

__global__ void transpose_fc(const float* __restrict__ w, float* __restrict__ wt) {
    int i = blockIdx.x * blockDim.x + threadIdx.x;
    if (i < O_ * H_) {
        int o = i / H_, k = i - o * H_;
        wt[k * O_ + o] = w[i];
    }
}

// ---------------------------------------------------------------- loaders

__device__ __forceinline__ void unpack4(const u64* d, bf16x8* hi, bf16x8* lo) {
    union { unsigned u[4]; bf16x8 v; } Hh, Ll;
    #pragma unroll
    for (int i = 0; i < 4; ++i) {
        unsigned lo32 = (unsigned)d[i], hi32 = (unsigned)(d[i] >> 32);
        Hh.u[i] = (lo32 & 0xFFFFu) | (hi32 << 16);
        Ll.u[i] = (lo32 >> 16) | (hi32 & 0xFFFF0000u);
    }
    *hi = Hh.v; *lo = Ll.v;
}

// sc1 LLC-coherent loads (state/h1 written mid-kernel by other blocks)
__device__ __forceinline__ void load_swz(const u64* p, bf16x8* hi, bf16x8* lo) {
    u64 d[4];
    #pragma unroll
    for (int i = 0; i < 4; ++i)
        d[i] = __hip_atomic_load((u64*)p + i * 16, __ATOMIC_RELAXED,
                                 __HIP_MEMORY_SCOPE_AGENT);
    unpack4(d, hi, lo);
}

// plain cached loads (x: written before kernel launch, LLC-visible)
__device__ __forceinline__ void load_swz_cached(const u64* p, bf16x8* hi, bf16x8* lo) {
    u64 d[4];
    #pragma unroll
    for (int i = 0; i < 4; ++i)
        d[i] = p[i * 16];
    unpack4(d, hi, lo);
}

// ---------------------------------------------------------------- step
// One layer step for one 32x32 tile. W register-resident (wh/wl), K-split 8.
// CPW chunks of 32 k per wave; chunks [0,SEG0CH) = seg0 (A0), rest = state.
template <int CPW, int SEG0CH, bool CACHED0>
__device__ __forceinline__ void step_full(
    const u64* __restrict__ A0,            // packed seg0 (xp_t or h1_{t-1})
    const u64* __restrict__ Sp,            // packed state (K=1024)
    const bf16x8 (&wh)[CPW][2], const bf16x8 (&wl)[CPW][2],
    const float* __restrict__ bs,
    u64* __restrict__ So, u64* __restrict__ Qo,
    int bt, int jt, int w, float* red)
{
    const int lane = threadIdx.x & 63;
    const int ln = lane & 15;
    const int q  = lane >> 4;

    f32x4 acc[2][2][3];
    #pragma unroll
    for (int s = 0; s < 2; ++s)
        #pragma unroll
        for (int n = 0; n < 2; ++n)
            #pragma unroll
            for (int r = 0; r < 3; ++r)
                acc[s][n][r] = (f32x4){0.f, 0.f, 0.f, 0.f};

    #pragma unroll
    for (int c = 0; c < CPW; ++c) {
        int gC = w * CPW + c;
        bf16x8 ah[2], al[2];
        if (gC < SEG0CH) {
            const u64* base = A0 + (long)(gC * 16 + q * 4) * 16 + ln;
            #pragma unroll
            for (int s = 0; s < 2; ++s) {
                const u64* p = base + (long)(bt * 2 + s) * (SEG0CH * 256);
                if (CACHED0) load_swz_cached(p, &ah[s], &al[s]);
                else         load_swz(p, &ah[s], &al[s]);
            }
        } else {
            const u64* base = Sp + (long)((gC - SEG0CH) * 16 + q * 4) * 16 + ln;
            #pragma unroll
            for (int s = 0; s < 2; ++s)
                load_swz(base + (long)(bt * 2 + s) * 8192, &ah[s], &al[s]);
        }
        #pragma unroll
        for (int s = 0; s < 2; ++s)
            #pragma unroll
            for (int n = 0; n < 2; ++n) {
                acc[s][n][0] = __builtin_amdgcn_mfma_f32_16x16x32_bf16(ah[s], wh[c][n], acc[s][n][0], 0, 0, 0);
                acc[s][n][1] = __builtin_amdgcn_mfma_f32_16x16x32_bf16(al[s], wh[c][n], acc[s][n][1], 0, 0, 0);
                acc[s][n][2] = __builtin_amdgcn_mfma_f32_16x16x32_bf16(ah[s], wl[c][n], acc[s][n][2], 0, 0, 0);
            }
    }

    // LDS reduce over 8 K-split waves (pad 33)
    {
        float* my = red + w * 1056;
        #pragma unroll
        for (int s = 0; s < 2; ++s)
            #pragma unroll
            for (int n = 0; n < 2; ++n) {
                f32x4 sum = acc[s][n][0] + acc[s][n][1] + acc[s][n][2];
                #pragma unroll
                for (int r = 0; r < 4; ++r)       // C/D: col=ln, row=q*4+r
                    my[(s * 16 + q * 4 + r) * 33 + n * 16 + ln] = sum[r];
            }
    }
    __syncthreads();

    // epilogue: 1024 outputs = 512 u64 (pairs), one per thread
    {
        int tid = threadIdx.x;
        int row = tid & 31;
        int jp  = tid >> 5;                 // 0..15
        int c0 = jp * 2;
        float v0 = 0.f, v1 = 0.f;
        #pragma unroll
        for (int w8 = 0; w8 < 8; ++w8) {
            v0 += red[w8 * 1056 + row * 33 + c0];
            v1 += red[w8 * 1056 + row * 33 + c0 + 1];
        }
        int j0 = jt * 32 + c0;
        float h0 = tanhf(v0 + bs[j0]);
        float h1v = tanhf(v1 + bs[j0 + 1]);
        union { __bf16 b; unsigned short u; } x0h, x0l, x1h, x1l;
        x0h.b = (__bf16)h0;  x0l.b = (__bf16)(h0 - (float)x0h.b);
        x1h.b = (__bf16)h1v; x1l.b = (__bf16)(h1v - (float)x1h.b);
        u64 pk = (u64)((unsigned)x0h.u | ((unsigned)x0l.u << 16))
               | ((u64)((unsigned)x1h.u | ((unsigned)x1l.u << 16)) << 32);
        long idx = (long)(bt * 2 + (row >> 4)) * 8192 + (long)(jt * 16 + jp) * 16 + (row & 15);
        __hip_atomic_store(&So[idx], pk, __ATOMIC_RELAXED, __HIP_MEMORY_SCOPE_AGENT);
        if (Qo)
            __hip_atomic_store(&Qo[idx], pk, __ATOMIC_RELAXED, __HIP_MEMORY_SCOPE_AGENT);
    }
}

// ---------------------------------------------------------------- barrier
// Fence-free (relaxed agent atomics meet at LLC; no buffer_inv/wbl2).
// 256 blocks = 8 grps x 32. Ordering: vmcnt drain (sc1 stores acked at LLC)
// before arrive.
__device__ __forceinline__ void grid_barrier(unsigned* bar, int grp, unsigned step) {
    asm volatile("s_waitcnt vmcnt(0)" ::: "memory");
    __syncthreads();
    if (threadIdx.x == 0) {
        unsigned tgt = step + 1u;
        unsigned old = __hip_atomic_fetch_add(&bar[grp * 32], 1u, __ATOMIC_RELAXED,
                                              __HIP_MEMORY_SCOPE_AGENT);
        if ((old & 31u) == 31u) {
            unsigned so = __hip_atomic_fetch_add(&bar[256], 1u, __ATOMIC_RELAXED,
                                                 __HIP_MEMORY_SCOPE_AGENT);
            if ((so & 7u) == 7u) {
                #pragma unroll
                for (int i = 0; i < 8; ++i)
                    __hip_atomic_store(&bar[512 + i * 32], tgt, __ATOMIC_RELAXED,
                                       __HIP_MEMORY_SCOPE_AGENT);
            }
        }
        while (__hip_atomic_load(&bar[512 + grp * 32], __ATOMIC_RELAXED,
                                 __HIP_MEMORY_SCOPE_AGENT) < tgt)
            __builtin_amdgcn_s_sleep(2);
    }
    __syncthreads();
    asm volatile("" ::: "memory");
}

// ---------------------------------------------------------------- persistent
struct PArgs {
    const u64* xp;                        // packed X [t][bt16][k2][ln]
    const __bf16 *Wi0h, *Wi0l, *Wr0h, *Wr0l;
    const __bf16 *Wi1h, *Wi1l, *Wr1h, *Wr1l;
    const float *bs0, *bs1;
    u64 *h1;                              // [t] stride 65536
    u64 *s0a, *s0b, *s1a, *s1b;
    unsigned* bar;
};

// 256 blocks x 512 threads (8 waves), 1 block/CU. 128 layer0 + 128 layer1
// blocks; per layer tiles: 4 bt (m=32) x 32 jt (n=32), K-split 8 over waves.
// Weights live in registers for the whole run (preloaded once).
__global__ __launch_bounds__(512, 2) void persistent_rnn(PArgs a) {
    __shared__ float red[8 * 1056];
    const int w = threadIdx.x >> 6;
    const int lane = threadIdx.x & 63;
    const int ln = lane & 15;
    const int q  = lane >> 4;
    const int grp = blockIdx.x & 7;
    const int layer = blockIdx.x >> 7;
    const int r7 = blockIdx.x & 127;
    const int jt = r7 & 31;
    const int bt = r7 >> 5;

    if (layer == 0) {
        // ---- preload W slice: chunks w*5 .. w*5+4 of Ktot=1280 (8 x-chunks, 32 rec)
        bf16x8 wh[5][2], wl[5][2];
        #pragma unroll
        for (int c = 0; c < 5; ++c) {
            int gC = w * 5 + c;
            #pragma unroll
            for (int n = 0; n < 2; ++n) {
                int jr = jt * 32 + n * 16 + ln;
                if (gC < 8) {
                    wh[c][n] = *(const bf16x8*)(a.Wi0h + (long)jr * 256 + gC * 32 + q * 8);
                    wl[c][n] = *(const bf16x8*)(a.Wi0l + (long)jr * 256 + gC * 32 + q * 8);
                } else {
                    wh[c][n] = *(const bf16x8*)(a.Wr0h + (long)jr * 1024 + (gC - 8) * 32 + q * 8);
                    wl[c][n] = *(const bf16x8*)(a.Wr0l + (long)jr * 1024 + (gC - 8) * 32 + q * 8);
                }
            }
        }
        for (int t = 0; t <= T_; ++t) {
            if (t < T_) {
                const u64* sin = (t & 1) ? a.s0b : a.s0a;
                u64* sout      = (t & 1) ? a.s0a : a.s0b;
                step_full<5, 8, true>(a.xp + (long)t * 16384, sin, wh, wl, a.bs0,
                                      sout, a.h1 + (long)t * 65536, bt, jt, w, red);
            }
            grid_barrier(a.bar, grp, (unsigned)t);
        }
    } else {
        // ---- preload W slice: chunks w*8 .. w*8+7 of Ktot=2048 (32 h1, 32 rec)
        bf16x8 wh[8][2], wl[8][2];
        #pragma unroll
        for (int c = 0; c < 8; ++c) {
            int gC = w * 8 + c;
            #pragma unroll
            for (int n = 0; n < 2; ++n) {
                int jr = jt * 32 + n * 16 + ln;
                if (gC < 32) {
                    wh[c][n] = *(const bf16x8*)(a.Wi1h + (long)jr * 1024 + gC * 32 + q * 8);
                    wl[c][n] = *(const bf16x8*)(a.Wi1l + (long)jr * 1024 + gC * 32 + q * 8);
                } else {
                    wh[c][n] = *(const bf16x8*)(a.Wr1h + (long)jr * 1024 + (gC - 32) * 32 + q * 8);
                    wl[c][n] = *(const bf16x8*)(a.Wr1l + (long)jr * 1024 + (gC - 32) * 32 + q * 8);
                }
            }
        }
        for (int t = 0; t <= T_; ++t) {
            if (t >= 1) {
                int t1 = t - 1;
                const u64* sin = (t1 & 1) ? a.s1b : a.s1a;
                u64* sout      = (t1 & 1) ? a.s1a : a.s1b;
                step_full<8, 32, false>(a.h1 + (long)t1 * 65536, sin, wh, wl, a.bs1,
                                        sout, (u64*)nullptr, bt, jt, w, red);
            }
            grid_barrier(a.bar, grp, (unsigned)t);
        }
    }
}

// ---------------------------------------------------------------- final FC
__global__ __launch_bounds__(128) void fc_kernel(const u64* __restrict__ sp,
                                                 const float* __restrict__ wt,
                                                 const float* __restrict__ bfc,
                                                 float* __restrict__ out) {
    int b = blockIdx.x;
    int o = threadIdx.x;
    int bt = b >> 4, r = b & 15;
    float acc = 0.f;
    #pragma unroll 4
    for (int k2 = 0; k2 < H_ / 2; ++k2) {
        u64 pk = __hip_atomic_load((u64*)sp + (long)bt * 8192 + (long)k2 * 16 + r,
                                   __ATOMIC_RELAXED, __HIP_MEMORY_SCOPE_AGENT);
        union { unsigned short u; __bf16 bf; } hh, hl;
        unsigned lo32 = (unsigned)pk, hi32 = (unsigned)(pk >> 32);
        hh.u = (unsigned short)(lo32 & 0xFFFF); hl.u = (unsigned short)(lo32 >> 16);
        float x0 = (float)hh.bf + (float)hl.bf;
        hh.u = (unsigned short)(hi32 & 0xFFFF); hl.u = (unsigned short)(hi32 >> 16);
        float x1 = (float)hh.bf + (float)hl.bf;
        acc += x0 * wt[(2 * k2) * O_ + o] + x1 * wt[(2 * k2 + 1) * O_ + o];
    }
    out[b * O_ + o] = acc + bfc[o];
}

// ---------------------------------------------------------------- launch

extern "C" void kernel_launch(void* const* d_in, const int* in_sizes, int n_in,
                              void* d_out, int out_size, void* d_ws, size_t ws_size,
                              hipStream_t stream) {
    const float* X     = (const float*)d_in[0];
    const float* Wih0  = (const float*)d_in[1];
    const float* Whh0  = (const float*)d_in[2];
    const float* bih0  = (const float*)d_in[3];
    const float* bhh0  = (const float*)d_in[4];
    const float* Wih1  = (const float*)d_in[5];
    const float* Whh1  = (const float*)d_in[6];
    const float* bih1  = (const float*)d_in[7];
    const float* bhh1  = (const float*)d_in[8];
    const float* Wfc   = (const float*)d_in[9];
    const float* bfc   = (const float*)d_in[10];
    float* out = (float*)d_out;

    char* p = (char*)d_ws;
    auto alloc = [&](size_t bytes) -> void* {
        void* r = (void*)p;
        p += (bytes + 255) & ~(size_t)255;
        return r;
    };
    const size_t nW0 = (size_t)H_ * I_;
    const size_t nW  = (size_t)H_ * H_;
    u64* xp      = (u64*)alloc((size_t)T_ * 16384 * 8);     // 33.5 MB
    __bf16* W0h  = (__bf16*)alloc(nW0 * 2);
    __bf16* W0l  = (__bf16*)alloc(nW0 * 2);
    __bf16* Wh0h = (__bf16*)alloc(nW * 2);
    __bf16* Wh0l = (__bf16*)alloc(nW * 2);
    __bf16* Wi1h = (__bf16*)alloc(nW * 2);
    __bf16* Wi1l = (__bf16*)alloc(nW * 2);
    __bf16* Wh1h = (__bf16*)alloc(nW * 2);
    __bf16* Wh1l = (__bf16*)alloc(nW * 2);
    u64* h1   = (u64*)alloc((size_t)T_ * 65536 * 8);        // 134 MB
    u64* s0a  = (u64*)alloc(65536 * 8);
    u64* s0b  = (u64*)alloc(65536 * 8);
    u64* s1a  = (u64*)alloc(65536 * 8);
    u64* s1b  = (u64*)alloc(65536 * 8);
    float* wfct = (float*)alloc((size_t)H_ * O_ * 4);
    float* bs0  = (float*)alloc((size_t)H_ * 4);
    float* bs1  = (float*)alloc((size_t)H_ * 4);
    unsigned* bar = (unsigned*)alloc(4096);
    (void)ws_size; (void)n_in; (void)in_sizes; (void)out_size;

    pack_x<<<16384, 256, 0, stream>>>(X, xp);
    split_kernel<<<512, 256, 0, stream>>>(Wih0, W0h, W0l, (int)nW0);
    split_kernel<<<1024, 256, 0, stream>>>(Whh0, Wh0h, Wh0l, (int)nW);
    split_kernel<<<1024, 256, 0, stream>>>(Wih1, Wi1h, Wi1l, (int)nW);
    split_kernel<<<1024, 256, 0, stream>>>(Whh1, Wh1h, Wh1l, (int)nW);
    bias_sum_kernel<<<4, 256, 0, stream>>>(bih0, bhh0, bs0, H_);
    bias_sum_kernel<<<4, 256, 0, stream>>>(bih1, bhh1, bs1, H_);
    transpose_fc<<<(O_ * H_ + 255) / 256, 256, 0, stream>>>(Wfc, wfct);

    hipMemsetAsync(s0a, 0, 65536 * 8, stream);
    hipMemsetAsync(s1a, 0, 65536 * 8, stream);
    hipMemsetAsync(bar, 0, 4096, stream);

    PArgs args;
    args.xp = xp;
    args.Wi0h = W0h; args.Wi0l = W0l; args.Wr0h = Wh0h; args.Wr0l = Wh0l;
    args.Wi1h = Wi1h; args.Wi1l = Wi1l; args.Wr1h = Wh1h; args.Wr1l = Wh1l;
    args.bs0 = bs0; args.bs1 = bs1;
    args.h1 = h1;
    args.s0a = s0a; args.s0b = s0b; args.s1a = s1a; args.s1b = s1b;
    args.bar = bar;
    void* kp[] = { &args };
    hipLaunchCooperativeKernel((void*)persistent_rnn, dim3(256), dim3(512), kp, 0, stream);

    // final layer1 state: last t1=255 (odd) wrote s1a
    fc_kernel<<<B_, O_, 0, stream>>>(s1a, wfct, bfc, out);
}